// Round 7
// baseline (583.341 us; speedup 1.0000x reference)
//
#include <hip/hip_runtime.h>
#include <math.h>

#define NROWS 8192
#define NCOLS 4096
#define NC4 1024          // NCOLS/4
#define EPS 1e-8f

// Scratch in device globals: graph-capture safe. Counters self-reset each call.
__device__ float g_partials[256 * NCOLS];  // [rowgroup][col] partials, 4 MB
__device__ float g_S[NCOLS];               // masked column sums
__device__ float g_n0[256];                // per-rowgroup label-0 counts
__device__ float g_msq4[4];                // per-quarter ||S||^2 partials
__device__ float g_A[1024];                // per-block sum mask0 * |dot|/xnorm
__device__ float g_B[1024];                // per-block sum mask1 * |dot|/xnorm
__device__ int   g_qcnt[4];                // per-quarter done counters (K1)
__device__ int   g_cnt;                    // done counter (K2)

// ---- K1: masked column partial sums + fused S-reduction tail ----
// 1024 blocks x 256: block b handles rowgroup rg=b>>2 (32 rows), quarter q=b&3
// (256 float4 cols). Last-arriving block per quarter reduces that quarter's
// 256 rowgroup partials into g_S (ONE int atomic per block — R4 lesson).
__global__ __launch_bounds__(256) void k_colsum(const float* __restrict__ labels,
                                                const float* __restrict__ datas) {
    const int b = blockIdx.x, t = threadIdx.x;
    const int rg = b >> 2, q = b & 3;
    const int r0 = rg * 32;
    __shared__ float m[32];
    __shared__ int idx[32];
    __shared__ int cntS;
    if (t < 32) {
        float l0 = labels[2 * (r0 + t)];
        float l1 = labels[2 * (r0 + t) + 1];
        m[t] = (l0 >= l1) ? 1.f : 0.f;     // argmax ties -> index 0
    }
    __syncthreads();
    if (t == 0) {
        int c = 0;
        #pragma unroll
        for (int r = 0; r < 32; ++r) if (m[r] != 0.f) idx[c++] = r0 + r;
        cntS = c;
        if (q == 0) g_n0[rg] = (float)c;
    }
    __syncthreads();
    const int cnt = cntS;
    const int coff = q * 256 + t;
    const float4* d4 = (const float4*)datas;
    float4 a0 = {0,0,0,0}, a1 = {0,0,0,0}, a2 = {0,0,0,0}, a3 = {0,0,0,0};
    int j = 0;
    for (; j + 3 < cnt; j += 4) {
        float4 v0 = d4[(size_t)idx[j]     * NC4 + coff];
        float4 v1 = d4[(size_t)idx[j + 1] * NC4 + coff];
        float4 v2 = d4[(size_t)idx[j + 2] * NC4 + coff];
        float4 v3 = d4[(size_t)idx[j + 3] * NC4 + coff];
        a0.x += v0.x; a0.y += v0.y; a0.z += v0.z; a0.w += v0.w;
        a1.x += v1.x; a1.y += v1.y; a1.z += v1.z; a1.w += v1.w;
        a2.x += v2.x; a2.y += v2.y; a2.z += v2.z; a2.w += v2.w;
        a3.x += v3.x; a3.y += v3.y; a3.z += v3.z; a3.w += v3.w;
    }
    for (; j < cnt; ++j) {
        float4 v = d4[(size_t)idx[j] * NC4 + coff];
        a0.x += v.x; a0.y += v.y; a0.z += v.z; a0.w += v.w;
    }
    a0.x += a1.x + a2.x + a3.x;
    a0.y += a1.y + a2.y + a3.y;
    a0.z += a1.z + a2.z + a3.z;
    a0.w += a1.w + a2.w + a3.w;
    ((float4*)g_partials)[(size_t)rg * NC4 + coff] = a0;

    // ---- fused reduceS: last block per quarter reduces its 1024 columns ----
    __threadfence();                       // release: partials visible device-wide
    __shared__ int lastS;
    if (t == 0) lastS = (atomicAdd(&g_qcnt[q], 1) == 255) ? 1 : 0;
    __syncthreads();
    if (lastS) {
        __threadfence();                   // acquire
        const int col4 = q * 256 + t;
        const float4* p4 = (const float4*)g_partials;
        float4 s = {0,0,0,0};
        #pragma unroll 16
        for (int rgi = 0; rgi < 256; ++rgi) {
            float4 v = p4[(size_t)rgi * NC4 + col4];
            s.x += v.x; s.y += v.y; s.z += v.z; s.w += v.w;
        }
        ((float4*)g_S)[col4] = s;
        float sq = s.x * s.x + s.y * s.y + s.z * s.z + s.w * s.w;
        #pragma unroll
        for (int off = 32; off; off >>= 1) sq += __shfl_xor(sq, off);
        __shared__ float shq[4];
        if ((t & 63) == 0) shq[t >> 6] = sq;
        __syncthreads();
        if (t == 0) {
            g_msq4[q] = shq[0] + shq[1] + shq[2] + shq[3];
            g_qcnt[q] = 0;                 // reset for next graph replay
        }
    }
}

// ---- K2: per-row |dot|/xnorm + fused final tail (1024 blocks x 256) ----
// Two rows per wave, S loads shared (R6 form). Last-done block reduces the
// per-block partials and writes the 3 outputs.
__global__ __launch_bounds__(256) void k_cos(const float* __restrict__ labels,
                                             const float* __restrict__ datas,
                                             float* __restrict__ out) {
    const int t = threadIdx.x, lane = t & 63, w = t >> 6;
    const int rA = blockIdx.x * 8 + w * 2;  // rows rA, rA+1
    const float4* d4 = (const float4*)datas;
    const float4* s4 = (const float4*)g_S;
    const size_t baseA = (size_t)rA * NC4;
    const size_t baseB = baseA + NC4;
    float dotA = 0.f, sqA = 0.f, dotB = 0.f, sqB = 0.f;
    float4 va[4], vb[4], sv[4];
    #pragma unroll
    for (int half = 0; half < 4; ++half) {
        const int k0 = half * 4;
        #pragma unroll
        for (int k = 0; k < 4; ++k) va[k] = d4[baseA + lane + ((k0 + k) << 6)];
        #pragma unroll
        for (int k = 0; k < 4; ++k) vb[k] = d4[baseB + lane + ((k0 + k) << 6)];
        #pragma unroll
        for (int k = 0; k < 4; ++k) sv[k] = s4[lane + ((k0 + k) << 6)];
        #pragma unroll
        for (int k = 0; k < 4; ++k) {
            dotA += va[k].x * sv[k].x + va[k].y * sv[k].y + va[k].z * sv[k].z + va[k].w * sv[k].w;
            sqA  += va[k].x * va[k].x + va[k].y * va[k].y + va[k].z * va[k].z + va[k].w * va[k].w;
            dotB += vb[k].x * sv[k].x + vb[k].y * sv[k].y + vb[k].z * sv[k].z + vb[k].w * sv[k].w;
            sqB  += vb[k].x * vb[k].x + vb[k].y * vb[k].y + vb[k].z * vb[k].z + vb[k].w * vb[k].w;
        }
    }
    #pragma unroll
    for (int off = 32; off; off >>= 1) {
        dotA += __shfl_xor(dotA, off);
        sqA  += __shfl_xor(sqA, off);
        dotB += __shfl_xor(dotB, off);
        sqB  += __shfl_xor(sqB, off);
    }
    __shared__ float shA[4], shB[4];
    if (lane == 0) {
        float aA = fabsf(dotA) / fmaxf(sqrtf(sqA), EPS);  // /||S|| deferred
        float aB = fabsf(dotB) / fmaxf(sqrtf(sqB), EPS);
        float lA0 = labels[2 * rA],     lA1 = labels[2 * rA + 1];
        float lB0 = labels[2 * rA + 2], lB1 = labels[2 * rA + 3];
        bool mA = (lA0 >= lA1), mB = (lB0 >= lB1);
        shA[w] = (mA ? aA : 0.f) + (mB ? aB : 0.f);
        shB[w] = (mA ? 0.f : aA) + (mB ? 0.f : aB);
    }
    __syncthreads();
    if (t == 0) {
        g_A[blockIdx.x] = shA[0] + shA[1] + shA[2] + shA[3];
        g_B[blockIdx.x] = shB[0] + shB[1] + shB[2] + shB[3];
    }

    // ---- fused final: last-done block reduces partials, writes outputs ----
    __threadfence();                       // release
    __shared__ int lastS;
    if (t == 0) lastS = (atomicAdd(&g_cnt, 1) == 1023) ? 1 : 0;
    __syncthreads();
    if (lastS) {
        __threadfence();                   // acquire
        float A = 0.f, B = 0.f;
        #pragma unroll
        for (int j = 0; j < 4; ++j) {
            A += g_A[t + 256 * j];
            B += g_B[t + 256 * j];
        }
        float n0 = g_n0[t];
        #pragma unroll
        for (int off = 32; off; off >>= 1) {
            A  += __shfl_xor(A, off);
            B  += __shfl_xor(B, off);
            n0 += __shfl_xor(n0, off);
        }
        __shared__ float sh[4][3];
        if (lane == 0) { sh[w][0] = A; sh[w][1] = B; sh[w][2] = n0; }
        __syncthreads();
        if (t == 0) {
            float At = sh[0][0] + sh[1][0] + sh[2][0] + sh[3][0];
            float Bt = sh[0][1] + sh[1][1] + sh[2][1] + sh[3][1];
            float n0t = sh[0][2] + sh[1][2] + sh[2][2] + sh[3][2];
            float mt = g_msq4[0] + g_msq4[1] + g_msq4[2] + g_msq4[3];
            float n1 = (float)NROWS - n0t;
            float n0d = fmaxf(n0t, 1.f), n1d = fmaxf(n1, 1.f);
            // n0d * max(||S||/n0d, eps) == max(||S||, n0d*eps)
            float D = fmaxf(sqrtf(mt), n0d * EPS);
            float simL = (n0t > 0.f) ? (n0t - At / D) / n0d : 0.f;
            float difL = (n0t > 0.f && n1 > 0.f) ? (Bt / D) / n1d : 0.f;
            out[0] = simL + difL;
            out[1] = simL;
            out[2] = difL;
            g_cnt = 0;                     // reset for next graph replay
        }
    }
}

extern "C" void kernel_launch(void* const* d_in, const int* in_sizes, int n_in,
                              void* d_out, int out_size, void* d_ws, size_t ws_size,
                              hipStream_t stream) {
    const float* labels = (const float*)d_in[0];
    const float* datas  = (const float*)d_in[1];
    float* out = (float*)d_out;

    k_colsum<<<1024, 256, 0, stream>>>(labels, datas);
    k_cos<<<1024, 256, 0, stream>>>(labels, datas, out);
}

// Round 9
// 206.650 us; speedup vs baseline: 2.8228x; 2.8228x over previous
//
#include <hip/hip_runtime.h>
#include <math.h>

#define NROWS 8192
#define NCOLS 4096
#define NC4 1024          // NCOLS/4
#define EPS 1e-8f

// Scratch in device globals: graph-capture safe, fully re-written every call.
// NO cross-block fences/atomics anywhere: R4/R7 showed device-scope fence
// patterns at >=1K-block scale cost 100+ us on gfx950. Launch boundaries are
// the cheap fence.
__device__ float g_partials[256 * NCOLS];  // [rowgroup][col] partials, 4 MB
__device__ float g_S[NCOLS];               // masked column sums
__device__ float g_n0[256];                // per-rowgroup label-0 counts
__device__ float g_A[1024];                // per-block sum mask0 * |dot|/xnorm
__device__ float g_B[1024];                // per-block sum mask1 * |dot|/xnorm

// ---- K1: masked column partial sums (1024 blocks x 256) ----
// Block b: rowgroup rg=b>>2 (32 rows), column quarter q=b&3 (256 float4 cols).
// 4 blocks/CU averages the binomial row-count imbalance; compact index list
// debranches the hot loop. (R5-proven form.)
__global__ __launch_bounds__(256) void k_colsum(const float* __restrict__ labels,
                                                const float* __restrict__ datas) {
    const int b = blockIdx.x, t = threadIdx.x;
    const int rg = b >> 2, q = b & 3;
    const int r0 = rg * 32;
    __shared__ float m[32];
    __shared__ int idx[32];
    __shared__ int cntS;
    if (t < 32) {
        float l0 = labels[2 * (r0 + t)];
        float l1 = labels[2 * (r0 + t) + 1];
        m[t] = (l0 >= l1) ? 1.f : 0.f;     // argmax ties -> index 0
    }
    __syncthreads();
    if (t == 0) {
        int c = 0;
        #pragma unroll
        for (int r = 0; r < 32; ++r) if (m[r] != 0.f) idx[c++] = r0 + r;
        cntS = c;
        if (q == 0) g_n0[rg] = (float)c;
    }
    __syncthreads();
    const int cnt = cntS;
    const int coff = q * 256 + t;
    const float4* d4 = (const float4*)datas;
    float4 a0 = {0,0,0,0}, a1 = {0,0,0,0}, a2 = {0,0,0,0}, a3 = {0,0,0,0};
    int j = 0;
    for (; j + 3 < cnt; j += 4) {
        float4 v0 = d4[(size_t)idx[j]     * NC4 + coff];
        float4 v1 = d4[(size_t)idx[j + 1] * NC4 + coff];
        float4 v2 = d4[(size_t)idx[j + 2] * NC4 + coff];
        float4 v3 = d4[(size_t)idx[j + 3] * NC4 + coff];
        a0.x += v0.x; a0.y += v0.y; a0.z += v0.z; a0.w += v0.w;
        a1.x += v1.x; a1.y += v1.y; a1.z += v1.z; a1.w += v1.w;
        a2.x += v2.x; a2.y += v2.y; a2.z += v2.z; a2.w += v2.w;
        a3.x += v3.x; a3.y += v3.y; a3.z += v3.z; a3.w += v3.w;
    }
    for (; j < cnt; ++j) {
        float4 v = d4[(size_t)idx[j] * NC4 + coff];
        a0.x += v.x; a0.y += v.y; a0.z += v.z; a0.w += v.w;
    }
    a0.x += a1.x + a2.x + a3.x;
    a0.y += a1.y + a2.y + a3.y;
    a0.z += a1.z + a2.z + a3.z;
    a0.w += a1.w + a2.w + a3.w;
    ((float4*)g_partials)[(size_t)rg * NC4 + coff] = a0;
}

// ---- K2: reduce partials -> S (64 blocks x 256), coalesced float4 ----
// Block b owns 16 float4 columns (64*16 = 1024 total ✓). Thread t:
// col4 = b*16 + (t&15) in [0,1024), sub = t>>4 covers rowgroups
// sub*16..sub*16+15. Each 16-lane group reads a contiguous 256 B segment.
__global__ __launch_bounds__(256) void k_reduceS() {
    const int t = threadIdx.x, b = blockIdx.x;
    const int col4 = b * 16 + (t & 15);     // float4 column, < 1024
    const int sub = t >> 4;                 // 16 subs x 16 rowgroups each
    const float4* p4 = (const float4*)g_partials;
    float4 s = {0, 0, 0, 0};
    #pragma unroll
    for (int j = 0; j < 16; ++j) {
        float4 v = p4[(size_t)(sub * 16 + j) * NC4 + col4];
        s.x += v.x; s.y += v.y; s.z += v.z; s.w += v.w;
    }
    __shared__ float4 sh[16][17];           // [sub][col] padded
    sh[sub][t & 15] = s;
    __syncthreads();
    if (t < 16) {                           // 16 lanes finish 16 float4 cols
        float4 tot = {0, 0, 0, 0};
        #pragma unroll
        for (int i = 0; i < 16; ++i) {
            float4 v = sh[i][t];
            tot.x += v.x; tot.y += v.y; tot.z += v.z; tot.w += v.w;
        }
        ((float4*)g_S)[b * 16 + t] = tot;   // < 1024 ✓
    }
}

// ---- K3: per-row |dot|/xnorm (1024 blocks x 256, two rows per wave) ----
// S loads shared between the two rows (halves S traffic, raises MLP).
// No LDS staging of S (L1 serves it), no atomics/fences.
__global__ __launch_bounds__(256) void k_cos(const float* __restrict__ labels,
                                             const float* __restrict__ datas) {
    const int t = threadIdx.x, lane = t & 63, w = t >> 6;
    const int rA = blockIdx.x * 8 + w * 2;  // rows rA, rA+1
    const float4* d4 = (const float4*)datas;
    const float4* s4 = (const float4*)g_S;
    const size_t baseA = (size_t)rA * NC4;
    const size_t baseB = baseA + NC4;
    float dotA = 0.f, sqA = 0.f, dotB = 0.f, sqB = 0.f;
    float4 va[4], vb[4], sv[4];
    #pragma unroll
    for (int half = 0; half < 4; ++half) {
        const int k0 = half * 4;
        #pragma unroll
        for (int k = 0; k < 4; ++k) va[k] = d4[baseA + lane + ((k0 + k) << 6)];
        #pragma unroll
        for (int k = 0; k < 4; ++k) vb[k] = d4[baseB + lane + ((k0 + k) << 6)];
        #pragma unroll
        for (int k = 0; k < 4; ++k) sv[k] = s4[lane + ((k0 + k) << 6)];
        #pragma unroll
        for (int k = 0; k < 4; ++k) {
            dotA += va[k].x * sv[k].x + va[k].y * sv[k].y + va[k].z * sv[k].z + va[k].w * sv[k].w;
            sqA  += va[k].x * va[k].x + va[k].y * va[k].y + va[k].z * va[k].z + va[k].w * va[k].w;
            dotB += vb[k].x * sv[k].x + vb[k].y * sv[k].y + vb[k].z * sv[k].z + vb[k].w * sv[k].w;
            sqB  += vb[k].x * vb[k].x + vb[k].y * vb[k].y + vb[k].z * vb[k].z + vb[k].w * vb[k].w;
        }
    }
    #pragma unroll
    for (int off = 32; off; off >>= 1) {
        dotA += __shfl_xor(dotA, off);
        sqA  += __shfl_xor(sqA, off);
        dotB += __shfl_xor(dotB, off);
        sqB  += __shfl_xor(sqB, off);
    }
    __shared__ float shA[4], shB[4];
    if (lane == 0) {
        float aA = fabsf(dotA) / fmaxf(sqrtf(sqA), EPS);  // /||S|| deferred
        float aB = fabsf(dotB) / fmaxf(sqrtf(sqB), EPS);
        float lA0 = labels[2 * rA],     lA1 = labels[2 * rA + 1];
        float lB0 = labels[2 * rA + 2], lB1 = labels[2 * rA + 3];
        bool mA = (lA0 >= lA1), mB = (lB0 >= lB1);
        shA[w] = (mA ? aA : 0.f) + (mB ? aB : 0.f);
        shB[w] = (mA ? 0.f : aA) + (mB ? 0.f : aB);
    }
    __syncthreads();
    if (t == 0) {
        g_A[blockIdx.x] = shA[0] + shA[1] + shA[2] + shA[3];
        g_B[blockIdx.x] = shB[0] + shB[1] + shB[2] + shB[3];
    }
}

// ---- K4: final scalar reduction -> 3 outputs (1 block x 1024) ----
// Computes ||S||^2 directly from g_S (4096 floats) — no g_msq plumbing.
__global__ __launch_bounds__(1024) void k_final(float* __restrict__ out) {
    const int t = threadIdx.x, lane = t & 63, w = t >> 6;
    float A = g_A[t];
    float B = g_B[t];
    float n0 = (t < 256) ? g_n0[t] : 0.f;
    float s0 = g_S[t];
    float s1 = g_S[t + 1024];
    float s2 = g_S[t + 2048];
    float s3 = g_S[t + 3072];
    float msq = s0 * s0 + s1 * s1 + s2 * s2 + s3 * s3;
    #pragma unroll
    for (int off = 32; off; off >>= 1) {
        A   += __shfl_xor(A, off);
        B   += __shfl_xor(B, off);
        n0  += __shfl_xor(n0, off);
        msq += __shfl_xor(msq, off);
    }
    __shared__ float sh[16][4];
    if (lane == 0) { sh[w][0] = A; sh[w][1] = B; sh[w][2] = n0; sh[w][3] = msq; }
    __syncthreads();
    if (t == 0) {
        float At = 0.f, Bt = 0.f, n0t = 0.f, mt = 0.f;
        #pragma unroll
        for (int i = 0; i < 16; ++i) {
            At += sh[i][0]; Bt += sh[i][1]; n0t += sh[i][2]; mt += sh[i][3];
        }
        float n1 = (float)NROWS - n0t;
        float n0d = fmaxf(n0t, 1.f), n1d = fmaxf(n1, 1.f);
        // n0d * max(||S||/n0d, eps) == max(||S||, n0d*eps)
        float D = fmaxf(sqrtf(mt), n0d * EPS);
        float simL = (n0t > 0.f) ? (n0t - At / D) / n0d : 0.f;
        float difL = (n0t > 0.f && n1 > 0.f) ? (Bt / D) / n1d : 0.f;
        out[0] = simL + difL;
        out[1] = simL;
        out[2] = difL;
    }
}

extern "C" void kernel_launch(void* const* d_in, const int* in_sizes, int n_in,
                              void* d_out, int out_size, void* d_ws, size_t ws_size,
                              hipStream_t stream) {
    const float* labels = (const float*)d_in[0];
    const float* datas  = (const float*)d_in[1];
    float* out = (float*)d_out;

    k_colsum<<<1024, 256, 0, stream>>>(labels, datas);
    k_reduceS<<<64, 256, 0, stream>>>();
    k_cos<<<1024, 256, 0, stream>>>(labels, datas);
    k_final<<<1, 1024, 0, stream>>>(out);
}